// Round 5
// baseline (13092.960 us; speedup 1.0000x reference)
//
#include <hip/hip_runtime.h>
#include <hip/hip_bf16.h>

#define B_ 128
#define T_ 256
#define D_ 256
#define H_ 1024
#define C_ 1000

typedef __attribute__((ext_vector_type(8))) short short8;
typedef __attribute__((ext_vector_type(4))) float floatx4;

static __device__ __forceinline__ unsigned short f2bf(float f) {
  unsigned int u = __builtin_bit_cast(unsigned int, f);
  u += 0x7fffu + ((u >> 16) & 1u);
  return (unsigned short)(u >> 16);
}
static __device__ __forceinline__ float bf2f(unsigned short s) {
  unsigned int u = ((unsigned int)s) << 16;
  return __builtin_bit_cast(float, u);
}
static __device__ __forceinline__ float sigm(float z) {
  return 1.0f / (1.0f + __expf(-z));
}
static __device__ __forceinline__ float tanh_fast(float z) {
  z = fminf(fmaxf(z, -15.f), 15.f);
  float e = __expf(2.f * z);
  return (e - 1.f) / (e + 1.f);
}

// ---------------------------------------------------------------------------
// Pack 8 weight matrices into bf16 B-fragment-linear layout:
// Wp[jb][kc][g][lane][i]  (jb<64, kc<40, g<4, lane<64, i<8)
// value = W_all[k = kc*32 + (lane>>4)*8 + i][col j = jb*16 + (lane&15)], gate g.
// k<1024 -> W_*h ; k>=1024 -> W_*x.
// ---------------------------------------------------------------------------
__global__ __launch_bounds__(256) void pack_w(
    const float* __restrict__ Wgx, const float* __restrict__ Wix,
    const float* __restrict__ Wfx, const float* __restrict__ Wox,
    const float* __restrict__ Wgh, const float* __restrict__ Wih,
    const float* __restrict__ Wfh, const float* __restrict__ Woh,
    unsigned short* __restrict__ Wp) {
  int t = blockIdx.x * blockDim.x + threadIdx.x;  // 655,360 threads
  int L = t & 63;
  int g = (t >> 6) & 3;
  int rest = t >> 8;        // jb*40 + kc
  int kc = rest % 40;
  int jb = rest / 40;
  int n = L & 15, q = L >> 4;
  int j = jb * 16 + n;
  const float* Wh = (g == 0) ? Wgh : (g == 1) ? Wih : (g == 2) ? Wfh : Woh;
  const float* Wx = (g == 0) ? Wgx : (g == 1) ? Wix : (g == 2) ? Wfx : Wox;
  int k0 = kc * 32 + q * 8;
  unsigned int w[4];
#pragma unroll
  for (int i = 0; i < 4; i++) {
    int ka = k0 + 2 * i, kb = k0 + 2 * i + 1;
    float fa = (ka < H_) ? Wh[(size_t)ka * H_ + j] : Wx[(size_t)(ka - H_) * H_ + j];
    float fb = (kb < H_) ? Wh[(size_t)kb * H_ + j] : Wx[(size_t)(kb - H_) * H_ + j];
    w[i] = (unsigned int)f2bf(fa) | ((unsigned int)f2bf(fb) << 16);
  }
  uint4 v = {w[0], w[1], w[2], w[3]};
  *((uint4*)(Wp + (size_t)t * 8)) = v;
}

// ---------------------------------------------------------------------------
// Pack x [B][T][D] fp32 -> xb bf16 A-fragment layout:
// xb[t][rt16][kcx][lane][i]: value = x[b = rt16*16+(lane&15)][t][d = kcx*32+(lane>>4)*8+i]
// ---------------------------------------------------------------------------
__global__ __launch_bounds__(256) void pack_x(const float* __restrict__ x,
                                              unsigned short* __restrict__ xb) {
  int idx = blockIdx.x * blockDim.x + threadIdx.x;  // 1,048,576 threads
  int d8 = idx & 31;
  int tt = (idx >> 5) & 255;
  int b = idx >> 13;
  const float* src = x + ((size_t)b * T_ + tt) * D_ + d8 * 8;
  int rt = b >> 4, kcx = d8 >> 2, q = d8 & 3, m = b & 15;
  size_t dst = ((((size_t)tt * 8 + rt) * 8 + kcx) * 64 + (q * 16 + m)) * 8;
  unsigned int w[4];
#pragma unroll
  for (int i = 0; i < 4; i++) {
    float fa = src[2 * i], fb = src[2 * i + 1];
    w[i] = (unsigned int)f2bf(fa) | ((unsigned int)f2bf(fb) << 16);
  }
  uint4 v = {w[0], w[1], w[2], w[3]};
  *((uint4*)(xb + dst)) = v;
}

// ---------------------------------------------------------------------------
// Persistent scan, PLAIN launch (256 blocks x 256 threads = 1 block/CU, all
// co-resident by capacity). Block b: jb = b & 63, rtp = b >> 6.
// Wave w = k-split, 40KB weight slice in 160 VGPRs. c-state in registers.
// Hand-rolled per-group (64-block) barrier with BOTH-side device fences:
// release fence (L2 writeback) in all threads before arrival, acquire fence
// (L1/L2 invalidate) in all threads after release from the spin.
// ---------------------------------------------------------------------------
__global__ __launch_bounds__(256, 1) void lstm_scan(
    unsigned short* __restrict__ h0, unsigned short* __restrict__ h1,
    const unsigned short* __restrict__ Wp, const unsigned short* __restrict__ xb,
    const float* __restrict__ bg, const float* __restrict__ bi,
    const float* __restrict__ bf_, const float* __restrict__ bo,
    unsigned int* __restrict__ barcnt) {
  __shared__ float lds_f[8192];  // 32 KB: partial[w][rt][g][lane][p]
  int tid = threadIdx.x;
  int w = tid >> 6;
  int lane = tid & 63;
  int b = blockIdx.x;
  int jb = b & 63;
  int rtp = b >> 6;           // group id (independent batch-row chain)
  int rt_g0 = rtp * 2;
  int rt_g1 = rtp * 2 + 1;

  // ---- preload weight slice into registers: 40 x short8 = 160 VGPRs ----
  short8 wf[40];
  {
    const short8* Bp = (const short8*)Wp + ((size_t)jb * 40 + w * 10) * 4 * 64 + lane;
#pragma unroll
    for (int kk = 0; kk < 10; kk++)
#pragma unroll
      for (int g = 0; g < 4; g++)
        wf[kk * 4 + g] = Bp[(size_t)(kk * 4 + g) * 64];
  }

  // ---- A-fragment offsets (short8 units) for this wave's k-slice ----
  int offA0[10], offA1[10], isH[10];
#pragma unroll
  for (int kk = 0; kk < 10; kk++) {
    int kc = w * 10 + kk;
    if (kc < 32) {
      isH[kk] = 1;
      offA0[kk] = (rt_g0 * 32 + kc) * 64 + lane;
      offA1[kk] = (rt_g1 * 32 + kc) * 64 + lane;
    } else {
      isH[kk] = 0;
      offA0[kk] = (rt_g0 * 8 + (kc - 32)) * 64 + lane;
      offA1[kk] = (rt_g1 * 8 + (kc - 32)) * 64 + lane;
    }
  }

  // ---- epilogue assignment: lane handles 2 (row,col) cells, fixed forever ----
  int col = lane & 15;
  int r0 = w * 8 + (lane >> 4);      // local row in [0,32)
  int r1 = r0 + 4;
  int j = jb * 16 + col;
  float vbg = bg[j], vbi = bi[j], vbf = bf_[j], vbo = bo[j];
  int rt0e = r0 >> 4, q0 = (r0 & 15) >> 2, p0 = r0 & 3;
  int rt1e = r1 >> 4, q1 = (r1 & 15) >> 2, p1 = r1 & 3;
  int rg0 = rtp * 32 + r0, rg1 = rtp * 32 + r1;
  size_t dst0 = ((size_t)((rg0 >> 4) * 32 + (j >> 5)) * 64 + ((j >> 3) & 3) * 16 + (rg0 & 15)) * 8 + (j & 7);
  size_t dst1 = ((size_t)((rg1 >> 4) * 32 + (j >> 5)) * 64 + ((j >> 3) & 3) * 16 + (rg1 & 15)) * 8 + (j & 7);
  float c0 = 0.f, c1 = 0.f;  // cell state: registers only, never memory

  unsigned int* cnt = barcnt + rtp * 16;  // 64B-separated per group

  for (int t = 0; t < T_; t++) {
    const short8* hb_r = (const short8*)((t & 1) ? h1 : h0);
    const short8* xt = (const short8*)xb + (size_t)t * 4096;
    unsigned short* hb_w = (t & 1) ? h0 : h1;

    floatx4 acc0g = {0,0,0,0}, acc0i = {0,0,0,0}, acc0f = {0,0,0,0}, acc0o = {0,0,0,0};
    floatx4 acc1g = {0,0,0,0}, acc1i = {0,0,0,0}, acc1f = {0,0,0,0}, acc1o = {0,0,0,0};
#pragma unroll
    for (int kk = 0; kk < 10; kk++) {
      const short8* base = isH[kk] ? hb_r : xt;
      short8 a0 = base[offA0[kk]];
      short8 a1 = base[offA1[kk]];
      acc0g = __builtin_amdgcn_mfma_f32_16x16x32_bf16(a0, wf[kk * 4 + 0], acc0g, 0, 0, 0);
      acc0i = __builtin_amdgcn_mfma_f32_16x16x32_bf16(a0, wf[kk * 4 + 1], acc0i, 0, 0, 0);
      acc0f = __builtin_amdgcn_mfma_f32_16x16x32_bf16(a0, wf[kk * 4 + 2], acc0f, 0, 0, 0);
      acc0o = __builtin_amdgcn_mfma_f32_16x16x32_bf16(a0, wf[kk * 4 + 3], acc0o, 0, 0, 0);
      acc1g = __builtin_amdgcn_mfma_f32_16x16x32_bf16(a1, wf[kk * 4 + 0], acc1g, 0, 0, 0);
      acc1i = __builtin_amdgcn_mfma_f32_16x16x32_bf16(a1, wf[kk * 4 + 1], acc1i, 0, 0, 0);
      acc1f = __builtin_amdgcn_mfma_f32_16x16x32_bf16(a1, wf[kk * 4 + 2], acc1f, 0, 0, 0);
      acc1o = __builtin_amdgcn_mfma_f32_16x16x32_bf16(a1, wf[kk * 4 + 3], acc1o, 0, 0, 0);
    }

    // stage partials: lds[((w*2+rt)*4+g)*64 + lane] as float4
    floatx4* L4 = (floatx4*)lds_f;
    L4[((w * 2 + 0) * 4 + 0) * 64 + lane] = acc0g;
    L4[((w * 2 + 0) * 4 + 1) * 64 + lane] = acc0i;
    L4[((w * 2 + 0) * 4 + 2) * 64 + lane] = acc0f;
    L4[((w * 2 + 0) * 4 + 3) * 64 + lane] = acc0o;
    L4[((w * 2 + 1) * 4 + 0) * 64 + lane] = acc1g;
    L4[((w * 2 + 1) * 4 + 1) * 64 + lane] = acc1i;
    L4[((w * 2 + 1) * 4 + 2) * 64 + lane] = acc1f;
    L4[((w * 2 + 1) * 4 + 3) * 64 + lane] = acc1o;
    __syncthreads();

    // epilogue: sum 4 k-split partials for my 2 cells, all 4 gates
    int lc0 = q0 * 16 + col, lc1 = q1 * 16 + col;
    float s0[4], s1[4];
#pragma unroll
    for (int g = 0; g < 4; g++) {
      float a = 0.f, c = 0.f;
#pragma unroll
      for (int wp = 0; wp < 4; wp++) {
        a += lds_f[((wp * 2 + rt0e) * 4 + g) * 256 + lc0 * 4 + p0];
        c += lds_f[((wp * 2 + rt1e) * 4 + g) * 256 + lc1 * 4 + p1];
      }
      s0[g] = a;
      s1[g] = c;
    }
    {
      float gg = tanh_fast(s0[0] + vbg);
      float ii = sigm(s0[1] + vbi);
      float ff = sigm(s0[2] + vbf);
      float oo = sigm(s0[3] + vbo);
      c0 = gg * ii + c0 * ff;
      hb_w[dst0] = f2bf(tanh_fast(c0) * oo);
    }
    {
      float gg = tanh_fast(s1[0] + vbg);
      float ii = sigm(s1[1] + vbi);
      float ff = sigm(s1[2] + vbf);
      float oo = sigm(s1[3] + vbo);
      c1 = gg * ii + c1 * ff;
      hb_w[dst1] = f2bf(tanh_fast(c1) * oo);
    }

    // ---- group barrier (64 blocks sharing this batch-row chain) ----
    __threadfence();   // RELEASE side, all threads: write-back dirty L2 lines
    __syncthreads();
    if (tid == 0) {
      __hip_atomic_fetch_add(cnt, 1u, __ATOMIC_RELEASE, __HIP_MEMORY_SCOPE_AGENT);
      unsigned int target = 64u * (unsigned int)(t + 1);
      while (__hip_atomic_load(cnt, __ATOMIC_ACQUIRE, __HIP_MEMORY_SCOPE_AGENT) < target) {
        __builtin_amdgcn_s_sleep(2);
      }
    }
    __syncthreads();
    __threadfence();   // ACQUIRE side, all threads: invalidate stale L1/L2 lines
  }
}

// ---------------------------------------------------------------------------
// Final projection p = h_T @ W_ph + b_p and row-wise log_softmax.
// ---------------------------------------------------------------------------
__global__ __launch_bounds__(256) void final_proj(const unsigned short* __restrict__ hB,
                                                  const float* __restrict__ Wph,
                                                  const float* __restrict__ bp,
                                                  float* __restrict__ out) {
  __shared__ float hrow[H_];
  __shared__ float red[256];
  int row = blockIdx.x, tid = threadIdx.x;
  int rt = row >> 4, m = row & 15;
#pragma unroll
  for (int i = 0; i < 4; i++) {
    int k = tid * 4 + i;
    size_t idx = ((size_t)(rt * 32 + (k >> 5)) * 64 + (((k >> 3) & 3) * 16 + m)) * 8 + (k & 7);
    hrow[k] = bf2f(hB[idx]);
  }
  __syncthreads();

  int c3 = (tid + 768 < C_) ? (tid + 768) : (C_ - 1);
  float a0 = 0.f, a1 = 0.f, a2 = 0.f, a3 = 0.f;
#pragma unroll 4
  for (int k = 0; k < H_; k++) {
    float hv = hrow[k];
    const float* wr = Wph + (size_t)k * C_;
    a0 += hv * wr[tid];
    a1 += hv * wr[tid + 256];
    a2 += hv * wr[tid + 512];
    a3 += hv * wr[c3];
  }
  a0 += bp[tid];
  a1 += bp[tid + 256];
  a2 += bp[tid + 512];
  a3 += bp[c3];

  bool v3 = (tid + 768 < C_);
  float mx = fmaxf(fmaxf(a0, a1), a2);
  if (v3) mx = fmaxf(mx, a3);
  red[tid] = mx;
  __syncthreads();
  for (int s = 128; s > 0; s >>= 1) {
    if (tid < s) red[tid] = fmaxf(red[tid], red[tid + s]);
    __syncthreads();
  }
  float M = red[0];
  __syncthreads();
  float se = __expf(a0 - M) + __expf(a1 - M) + __expf(a2 - M);
  if (v3) se += __expf(a3 - M);
  red[tid] = se;
  __syncthreads();
  for (int s = 128; s > 0; s >>= 1) {
    if (tid < s) red[tid] += red[tid + s];
    __syncthreads();
  }
  float lse = M + logf(red[0]);
  out[(size_t)row * C_ + tid] = a0 - lse;
  out[(size_t)row * C_ + tid + 256] = a1 - lse;
  out[(size_t)row * C_ + tid + 512] = a2 - lse;
  if (v3) out[(size_t)row * C_ + tid + 768] = a3 - lse;
}

extern "C" void kernel_launch(void* const* d_in, const int* in_sizes, int n_in,
                              void* d_out, int out_size, void* d_ws, size_t ws_size,
                              hipStream_t stream) {
  const float* x   = (const float*)d_in[0];
  const float* Wgx = (const float*)d_in[1];
  const float* Wix = (const float*)d_in[2];
  const float* Wfx = (const float*)d_in[3];
  const float* Wox = (const float*)d_in[4];
  const float* Wgh = (const float*)d_in[5];
  const float* Wih = (const float*)d_in[6];
  const float* Wfh = (const float*)d_in[7];
  const float* Woh = (const float*)d_in[8];
  const float* Wph = (const float*)d_in[9];
  const float* bg  = (const float*)d_in[10];
  const float* bi  = (const float*)d_in[11];
  const float* bf  = (const float*)d_in[12];
  const float* bo  = (const float*)d_in[13];
  const float* bp  = (const float*)d_in[14];

  char* ws = (char*)d_ws;
  unsigned short* Wp = (unsigned short*)ws;                 // 10,485,760 B
  size_t off = 10485760;
  unsigned short* xb = (unsigned short*)(ws + off); off += 16777216;  // 16 MB
  unsigned short* h0 = (unsigned short*)(ws + off); off += 262144;
  unsigned short* h1 = (unsigned short*)(ws + off); off += 262144;
  unsigned int* cnt = (unsigned int*)(ws + off); off += 256;

  hipMemsetAsync(h0, 0, 262144, stream);
  hipMemsetAsync((void*)cnt, 0, 256, stream);

  pack_w<<<2560, 256, 0, stream>>>(Wgx, Wix, Wfx, Wox, Wgh, Wih, Wfh, Woh, Wp);
  pack_x<<<4096, 256, 0, stream>>>(x, xb);

  lstm_scan<<<256, 256, 0, stream>>>(h0, h1, Wp, xb, bg, bi, bf, bo, cnt);

  // after 256 steps final h is in h0
  final_proj<<<128, 256, 0, stream>>>(h0, Wph, bp, (float*)d_out);
}

// Round 6
// 3606.863 us; speedup vs baseline: 3.6300x; 3.6300x over previous
//
#include <hip/hip_runtime.h>
#include <hip/hip_bf16.h>

#define B_ 128
#define T_ 256
#define D_ 256
#define H_ 1024
#define C_ 1000

typedef __attribute__((ext_vector_type(8))) short short8;
typedef __attribute__((ext_vector_type(4))) float floatx4;

static __device__ __forceinline__ unsigned short f2bf(float f) {
  unsigned int u = __builtin_bit_cast(unsigned int, f);
  u += 0x7fffu + ((u >> 16) & 1u);
  return (unsigned short)(u >> 16);
}
static __device__ __forceinline__ float bf2f(unsigned short s) {
  unsigned int u = ((unsigned int)s) << 16;
  return __builtin_bit_cast(float, u);
}
static __device__ __forceinline__ float sigm(float z) {
  return 1.0f / (1.0f + __expf(-z));
}
static __device__ __forceinline__ float tanh_fast(float z) {
  z = fminf(fmaxf(z, -15.f), 15.f);
  float e = __expf(2.f * z);
  return (e - 1.f) / (e + 1.f);
}

// ---------------------------------------------------------------------------
// Pack 8 weight matrices into bf16 B-fragment-linear layout:
// Wp[jb][kc][g][lane][i]  (jb<64, kc<40, g<4, lane<64, i<8)
// value = W_all[k = kc*32 + (lane>>4)*8 + i][col j = jb*16 + (lane&15)], gate g.
// k<1024 -> W_*h ; k>=1024 -> W_*x.
// ---------------------------------------------------------------------------
__global__ __launch_bounds__(256) void pack_w(
    const float* __restrict__ Wgx, const float* __restrict__ Wix,
    const float* __restrict__ Wfx, const float* __restrict__ Wox,
    const float* __restrict__ Wgh, const float* __restrict__ Wih,
    const float* __restrict__ Wfh, const float* __restrict__ Woh,
    unsigned short* __restrict__ Wp) {
  int t = blockIdx.x * blockDim.x + threadIdx.x;  // 655,360 threads
  int L = t & 63;
  int g = (t >> 6) & 3;
  int rest = t >> 8;        // jb*40 + kc
  int kc = rest % 40;
  int jb = rest / 40;
  int n = L & 15, q = L >> 4;
  int j = jb * 16 + n;
  const float* Wh = (g == 0) ? Wgh : (g == 1) ? Wih : (g == 2) ? Wfh : Woh;
  const float* Wx = (g == 0) ? Wgx : (g == 1) ? Wix : (g == 2) ? Wfx : Wox;
  int k0 = kc * 32 + q * 8;
  unsigned int w[4];
#pragma unroll
  for (int i = 0; i < 4; i++) {
    int ka = k0 + 2 * i, kb = k0 + 2 * i + 1;
    float fa = (ka < H_) ? Wh[(size_t)ka * H_ + j] : Wx[(size_t)(ka - H_) * H_ + j];
    float fb = (kb < H_) ? Wh[(size_t)kb * H_ + j] : Wx[(size_t)(kb - H_) * H_ + j];
    w[i] = (unsigned int)f2bf(fa) | ((unsigned int)f2bf(fb) << 16);
  }
  uint4 v = {w[0], w[1], w[2], w[3]};
  *((uint4*)(Wp + (size_t)t * 8)) = v;
}

// ---------------------------------------------------------------------------
// Pack x [B][T][D] fp32 -> xb bf16 A-fragment layout:
// xb[t][rt16][kcx][lane][i]: value = x[b = rt16*16+(lane&15)][t][d = kcx*32+(lane>>4)*8+i]
// ---------------------------------------------------------------------------
__global__ __launch_bounds__(256) void pack_x(const float* __restrict__ x,
                                              unsigned short* __restrict__ xb) {
  int idx = blockIdx.x * blockDim.x + threadIdx.x;  // 1,048,576 threads
  int d8 = idx & 31;
  int tt = (idx >> 5) & 255;
  int b = idx >> 13;
  const float* src = x + ((size_t)b * T_ + tt) * D_ + d8 * 8;
  int rt = b >> 4, kcx = d8 >> 2, q = d8 & 3, m = b & 15;
  size_t dst = ((((size_t)tt * 8 + rt) * 8 + kcx) * 64 + (q * 16 + m)) * 8;
  unsigned int w[4];
#pragma unroll
  for (int i = 0; i < 4; i++) {
    float fa = src[2 * i], fb = src[2 * i + 1];
    w[i] = (unsigned int)f2bf(fa) | ((unsigned int)f2bf(fb) << 16);
  }
  uint4 v = {w[0], w[1], w[2], w[3]};
  *((uint4*)(xb + dst)) = v;
}

// ---------------------------------------------------------------------------
// Persistent scan, PLAIN launch (256 blocks x 256 threads = 1 block/CU, all
// co-resident by capacity). Block b: jb = b & 63, rtp = b >> 6.
// Wave w = k-split, 40KB weight slice in 160 VGPRs. c-state in registers.
// Lightweight per-group (64-block) barrier: NO per-thread fences (the R5
// version's all-thread __threadfence() storm of buffer_wbl2/inv was the
// 50us/step killer). Protocol: plain stores -> vmcnt(0)+syncthreads (stores
// in L2) -> tid0 RELEASE fetch_add (one wbl2/block) -> tid0 RELAXED spin
// (LLC reads, no invalidates) -> tid0 ACQUIRE load (one inv/block) ->
// syncthreads.
// ---------------------------------------------------------------------------
__global__ __launch_bounds__(256, 1) void lstm_scan(
    unsigned short* __restrict__ h0, unsigned short* __restrict__ h1,
    const unsigned short* __restrict__ Wp, const unsigned short* __restrict__ xb,
    const float* __restrict__ bg, const float* __restrict__ bi,
    const float* __restrict__ bf_, const float* __restrict__ bo,
    unsigned int* __restrict__ barcnt) {
  __shared__ float lds_f[8192];  // 32 KB: partial[w][rt][g][lane][p]
  int tid = threadIdx.x;
  int w = tid >> 6;
  int lane = tid & 63;
  int b = blockIdx.x;
  int jb = b & 63;
  int rtp = b >> 6;           // group id (independent batch-row chain)
  int rt_g0 = rtp * 2;
  int rt_g1 = rtp * 2 + 1;

  // ---- preload weight slice into registers: 40 x short8 = 160 VGPRs ----
  short8 wf[40];
  {
    const short8* Bp = (const short8*)Wp + ((size_t)jb * 40 + w * 10) * 4 * 64 + lane;
#pragma unroll
    for (int kk = 0; kk < 10; kk++)
#pragma unroll
      for (int g = 0; g < 4; g++)
        wf[kk * 4 + g] = Bp[(size_t)(kk * 4 + g) * 64];
  }

  // ---- A-fragment offsets (short8 units) for this wave's k-slice ----
  int offA0[10], offA1[10], isH[10];
#pragma unroll
  for (int kk = 0; kk < 10; kk++) {
    int kc = w * 10 + kk;
    if (kc < 32) {
      isH[kk] = 1;
      offA0[kk] = (rt_g0 * 32 + kc) * 64 + lane;
      offA1[kk] = (rt_g1 * 32 + kc) * 64 + lane;
    } else {
      isH[kk] = 0;
      offA0[kk] = (rt_g0 * 8 + (kc - 32)) * 64 + lane;
      offA1[kk] = (rt_g1 * 8 + (kc - 32)) * 64 + lane;
    }
  }

  // ---- epilogue assignment: lane handles 2 (row,col) cells, fixed forever ----
  int col = lane & 15;
  int r0 = w * 8 + (lane >> 4);      // local row in [0,32)
  int r1 = r0 + 4;
  int j = jb * 16 + col;
  float vbg = bg[j], vbi = bi[j], vbf = bf_[j], vbo = bo[j];
  int rt0e = r0 >> 4, q0 = (r0 & 15) >> 2, p0 = r0 & 3;
  int rt1e = r1 >> 4, q1 = (r1 & 15) >> 2, p1 = r1 & 3;
  int rg0 = rtp * 32 + r0, rg1 = rtp * 32 + r1;
  size_t dst0 = ((size_t)((rg0 >> 4) * 32 + (j >> 5)) * 64 + ((j >> 3) & 3) * 16 + (rg0 & 15)) * 8 + (j & 7);
  size_t dst1 = ((size_t)((rg1 >> 4) * 32 + (j >> 5)) * 64 + ((j >> 3) & 3) * 16 + (rg1 & 15)) * 8 + (j & 7);
  float c0 = 0.f, c1 = 0.f;  // cell state: registers only, never memory

  unsigned int* cnt = barcnt + rtp * 16;  // 64B-separated per group

  for (int t = 0; t < T_; t++) {
    const short8* hb_r = (const short8*)((t & 1) ? h1 : h0);
    const short8* xt = (const short8*)xb + (size_t)t * 4096;
    unsigned short* hb_w = (t & 1) ? h0 : h1;

    floatx4 acc0g = {0,0,0,0}, acc0i = {0,0,0,0}, acc0f = {0,0,0,0}, acc0o = {0,0,0,0};
    floatx4 acc1g = {0,0,0,0}, acc1i = {0,0,0,0}, acc1f = {0,0,0,0}, acc1o = {0,0,0,0};
#pragma unroll
    for (int kk = 0; kk < 10; kk++) {
      const short8* base = isH[kk] ? hb_r : xt;
      short8 a0 = base[offA0[kk]];
      short8 a1 = base[offA1[kk]];
      acc0g = __builtin_amdgcn_mfma_f32_16x16x32_bf16(a0, wf[kk * 4 + 0], acc0g, 0, 0, 0);
      acc0i = __builtin_amdgcn_mfma_f32_16x16x32_bf16(a0, wf[kk * 4 + 1], acc0i, 0, 0, 0);
      acc0f = __builtin_amdgcn_mfma_f32_16x16x32_bf16(a0, wf[kk * 4 + 2], acc0f, 0, 0, 0);
      acc0o = __builtin_amdgcn_mfma_f32_16x16x32_bf16(a0, wf[kk * 4 + 3], acc0o, 0, 0, 0);
      acc1g = __builtin_amdgcn_mfma_f32_16x16x32_bf16(a1, wf[kk * 4 + 0], acc1g, 0, 0, 0);
      acc1i = __builtin_amdgcn_mfma_f32_16x16x32_bf16(a1, wf[kk * 4 + 1], acc1i, 0, 0, 0);
      acc1f = __builtin_amdgcn_mfma_f32_16x16x32_bf16(a1, wf[kk * 4 + 2], acc1f, 0, 0, 0);
      acc1o = __builtin_amdgcn_mfma_f32_16x16x32_bf16(a1, wf[kk * 4 + 3], acc1o, 0, 0, 0);
    }

    // stage partials: lds[((w*2+rt)*4+g)*64 + lane] as float4
    floatx4* L4 = (floatx4*)lds_f;
    L4[((w * 2 + 0) * 4 + 0) * 64 + lane] = acc0g;
    L4[((w * 2 + 0) * 4 + 1) * 64 + lane] = acc0i;
    L4[((w * 2 + 0) * 4 + 2) * 64 + lane] = acc0f;
    L4[((w * 2 + 0) * 4 + 3) * 64 + lane] = acc0o;
    L4[((w * 2 + 1) * 4 + 0) * 64 + lane] = acc1g;
    L4[((w * 2 + 1) * 4 + 1) * 64 + lane] = acc1i;
    L4[((w * 2 + 1) * 4 + 2) * 64 + lane] = acc1f;
    L4[((w * 2 + 1) * 4 + 3) * 64 + lane] = acc1o;
    __syncthreads();

    // epilogue: sum 4 k-split partials for my 2 cells, all 4 gates
    int lc0 = q0 * 16 + col, lc1 = q1 * 16 + col;
    float s0[4], s1[4];
#pragma unroll
    for (int g = 0; g < 4; g++) {
      float a = 0.f, c = 0.f;
#pragma unroll
      for (int wp = 0; wp < 4; wp++) {
        a += lds_f[((wp * 2 + rt0e) * 4 + g) * 256 + lc0 * 4 + p0];
        c += lds_f[((wp * 2 + rt1e) * 4 + g) * 256 + lc1 * 4 + p1];
      }
      s0[g] = a;
      s1[g] = c;
    }
    {
      float gg = tanh_fast(s0[0] + vbg);
      float ii = sigm(s0[1] + vbi);
      float ff = sigm(s0[2] + vbf);
      float oo = sigm(s0[3] + vbo);
      c0 = gg * ii + c0 * ff;
      hb_w[dst0] = f2bf(tanh_fast(c0) * oo);
    }
    {
      float gg = tanh_fast(s1[0] + vbg);
      float ii = sigm(s1[1] + vbi);
      float ff = sigm(s1[2] + vbf);
      float oo = sigm(s1[3] + vbo);
      c1 = gg * ii + c1 * ff;
      hb_w[dst1] = f2bf(tanh_fast(c1) * oo);
    }

    // ---- lightweight group barrier (64 blocks of this batch-row chain) ----
    __asm__ __volatile__("s_waitcnt vmcnt(0)" ::: "memory");  // my stores -> L2
    __syncthreads();                                          // whole block stored
    if (tid == 0) {
      // RELEASE: one buffer_wbl2 for the block's L2-resident h stores + add at LLC
      __hip_atomic_fetch_add(cnt, 1u, __ATOMIC_RELEASE, __HIP_MEMORY_SCOPE_AGENT);
      unsigned int target = 64u * (unsigned int)(t + 1);
      // RELAXED spin: LLC reads only, no cache invalidates per poll
      while (__hip_atomic_load(cnt, __ATOMIC_RELAXED, __HIP_MEMORY_SCOPE_AGENT) < target) {
        __builtin_amdgcn_s_sleep(8);
      }
      // ACQUIRE: one buffer_inv so this CU's L1/XCD L2 drop stale h lines
      (void)__hip_atomic_load(cnt, __ATOMIC_ACQUIRE, __HIP_MEMORY_SCOPE_AGENT);
    }
    __syncthreads();
  }
}

// ---------------------------------------------------------------------------
// Final projection p = h_T @ W_ph + b_p and row-wise log_softmax.
// ---------------------------------------------------------------------------
__global__ __launch_bounds__(256) void final_proj(const unsigned short* __restrict__ hB,
                                                  const float* __restrict__ Wph,
                                                  const float* __restrict__ bp,
                                                  float* __restrict__ out) {
  __shared__ float hrow[H_];
  __shared__ float red[256];
  int row = blockIdx.x, tid = threadIdx.x;
  int rt = row >> 4, m = row & 15;
#pragma unroll
  for (int i = 0; i < 4; i++) {
    int k = tid * 4 + i;
    size_t idx = ((size_t)(rt * 32 + (k >> 5)) * 64 + (((k >> 3) & 3) * 16 + m)) * 8 + (k & 7);
    hrow[k] = bf2f(hB[idx]);
  }
  __syncthreads();

  int c3 = (tid + 768 < C_) ? (tid + 768) : (C_ - 1);
  float a0 = 0.f, a1 = 0.f, a2 = 0.f, a3 = 0.f;
#pragma unroll 4
  for (int k = 0; k < H_; k++) {
    float hv = hrow[k];
    const float* wr = Wph + (size_t)k * C_;
    a0 += hv * wr[tid];
    a1 += hv * wr[tid + 256];
    a2 += hv * wr[tid + 512];
    a3 += hv * wr[c3];
  }
  a0 += bp[tid];
  a1 += bp[tid + 256];
  a2 += bp[tid + 512];
  a3 += bp[c3];

  bool v3 = (tid + 768 < C_);
  float mx = fmaxf(fmaxf(a0, a1), a2);
  if (v3) mx = fmaxf(mx, a3);
  red[tid] = mx;
  __syncthreads();
  for (int s = 128; s > 0; s >>= 1) {
    if (tid < s) red[tid] = fmaxf(red[tid], red[tid + s]);
    __syncthreads();
  }
  float M = red[0];
  __syncthreads();
  float se = __expf(a0 - M) + __expf(a1 - M) + __expf(a2 - M);
  if (v3) se += __expf(a3 - M);
  red[tid] = se;
  __syncthreads();
  for (int s = 128; s > 0; s >>= 1) {
    if (tid < s) red[tid] += red[tid + s];
    __syncthreads();
  }
  float lse = M + logf(red[0]);
  out[(size_t)row * C_ + tid] = a0 - lse;
  out[(size_t)row * C_ + tid + 256] = a1 - lse;
  out[(size_t)row * C_ + tid + 512] = a2 - lse;
  if (v3) out[(size_t)row * C_ + tid + 768] = a3 - lse;
}

extern "C" void kernel_launch(void* const* d_in, const int* in_sizes, int n_in,
                              void* d_out, int out_size, void* d_ws, size_t ws_size,
                              hipStream_t stream) {
  const float* x   = (const float*)d_in[0];
  const float* Wgx = (const float*)d_in[1];
  const float* Wix = (const float*)d_in[2];
  const float* Wfx = (const float*)d_in[3];
  const float* Wox = (const float*)d_in[4];
  const float* Wgh = (const float*)d_in[5];
  const float* Wih = (const float*)d_in[6];
  const float* Wfh = (const float*)d_in[7];
  const float* Woh = (const float*)d_in[8];
  const float* Wph = (const float*)d_in[9];
  const float* bg  = (const float*)d_in[10];
  const float* bi  = (const float*)d_in[11];
  const float* bf  = (const float*)d_in[12];
  const float* bo  = (const float*)d_in[13];
  const float* bp  = (const float*)d_in[14];

  char* ws = (char*)d_ws;
  unsigned short* Wp = (unsigned short*)ws;                 // 10,485,760 B
  size_t off = 10485760;
  unsigned short* xb = (unsigned short*)(ws + off); off += 16777216;  // 16 MB
  unsigned short* h0 = (unsigned short*)(ws + off); off += 262144;
  unsigned short* h1 = (unsigned short*)(ws + off); off += 262144;
  unsigned int* cnt = (unsigned int*)(ws + off); off += 256;

  hipMemsetAsync(h0, 0, 262144, stream);
  hipMemsetAsync((void*)cnt, 0, 256, stream);

  pack_w<<<2560, 256, 0, stream>>>(Wgx, Wix, Wfx, Wox, Wgh, Wih, Wfh, Woh, Wp);
  pack_x<<<4096, 256, 0, stream>>>(x, xb);

  lstm_scan<<<256, 256, 0, stream>>>(h0, h1, Wp, xb, bg, bi, bf, bo, cnt);

  // after 256 steps final h is in h0
  final_proj<<<128, 256, 0, stream>>>(h0, Wph, bp, (float*)d_out);
}